// Round 13
// baseline (63.954 us; speedup 1.0000x reference)
//
#include <hip/hip_runtime.h>
#include <hip/hip_bf16.h>

#define NAG 8
#define BATCH 32768
#define DDIM 128
#define ADIM 64
#define HDIM 128

#define NJ1 11            // layer1 col tiles: 128 (W1) + 32 (Wc1) + 1 (Ws1) -> 176 cols
#define NJ2 8
#define NJ3 4
#define FB_L1 (NJ1*4)     // 44 frag blocks (44KB)
#define FB_L2 (NJ2*4)     // 32
#define FB_L3 (NJ3*4)     // 16
#define FB_TOT (FB_L1+FB_L2+FB_L3)  // 92
#define WAGENT (FB_TOT*512)         // 47104 ushort per agent (92KB)

typedef __attribute__((ext_vector_type(8))) short bf16x8;
typedef __attribute__((ext_vector_type(4))) float f32x4;
typedef __attribute__((ext_vector_type(4))) unsigned int u32x4;

static __device__ __forceinline__ unsigned short f2bf(float f) {
  unsigned int u = __builtin_bit_cast(unsigned int, f);
  u += 0x7fffu + ((u >> 16) & 1u);          // RNE (inputs are finite)
  return (unsigned short)(u >> 16);
}

static __device__ __forceinline__ unsigned int cvt_pk_bf16(float a, float b) {
  unsigned int r;
  asm("v_cvt_pk_bf16_f32 %0, %1, %2" : "=v"(r) : "v"(a), "v"(b));
  return r;
}

// single-value f32->bf16 via one cvt_pk op (RNE), low 16 bits valid
static __device__ __forceinline__ unsigned short f2bf1(float f) {
  unsigned int r;
  asm("v_cvt_pk_bf16_f32 %0, %1, %2" : "=v"(r) : "v"(f), "v"(f));
  return (unsigned short)r;
}

// async global->LDS, 16B per lane; LDS dest = uniform base + lane*16 (linear)
static __device__ __forceinline__ void gload_lds16(const void* g, void* l) {
  __builtin_amdgcn_global_load_lds(
      (const __attribute__((address_space(1))) unsigned int*)g,
      (__attribute__((address_space(3))) unsigned int*)l, 16, 0, 0);
}

// ---------------- prep: f32 weights -> bf16 B-fragment-linear layout (proven) ----------------
// frag block fb=(j,kk): 512 bf16; element l*8+t = W[k = kk*32 + (l>>4)*8 + t][col = j*16 + (l&15)]
__global__ void __launch_bounds__(256)
prep_weights(const float* __restrict__ W1, const float* __restrict__ W2,
             const float* __restrict__ W3, const float* __restrict__ Wc1,
             const float* __restrict__ Ws1, const float* __restrict__ b1,
             const float* __restrict__ bc1, const float* __restrict__ bs1,
             unsigned short* __restrict__ wbuf, float* __restrict__ b1e)
{
  int tid = blockIdx.x * 256 + threadIdx.x;
  if (tid < NAG * WAGENT) {
    int agent = tid / WAGENT;
    int rem   = tid % WAGENT;
    int fb = rem >> 9;
    int li = rem & 511;
    int l = li >> 3, t = li & 7;
    int lr = l & 15, lg = l >> 4;
    float v = 0.0f;
    if (fb < FB_L1) {
      int j = fb >> 2, kk = fb & 3;
      int col = j*16 + lr, k = kk*32 + lg*8 + t;
      if (col < 128)       v = W1[((size_t)agent*128 + k)*128 + col];
      else if (col < 160)  v = Wc1[k*32 + (col-128)];
      else if (col == 160) v = Ws1[k];
    } else if (fb < FB_L1 + FB_L2) {
      int f = fb - FB_L1;
      int j = f >> 2, kk = f & 3;
      int col = j*16 + lr, k = kk*32 + lg*8 + t;
      v = W2[((size_t)agent*128 + k)*128 + col];
    } else {
      int f = fb - FB_L1 - FB_L2;
      int j = f >> 2, kk = f & 3;
      int col = j*16 + lr, k = kk*32 + lg*8 + t;
      v = W3[((size_t)agent*128 + k)*64 + col];
    }
    wbuf[tid] = f2bf(v);
  }
  if (tid < NAG * 176) {     // extended layer-1 bias: [b1 | bc1 | bs1 | 0]
    int agent = tid / 176, col = tid % 176;
    float v = 0.0f;
    if (col < 128)       v = b1[agent*128 + col];
    else if (col < 160)  v = bc1[col - 128];
    else if (col == 160) v = bs1[0];
    b1e[tid] = v;
  }
}

// ---------------- main: 2 blocks/CU, bufMain(L1/L2) + bufL3 split, covered staging ----------
// 512 blocks x 256 threads (4 waves), 2 blocks/CU (LDS 76KB). Wave w owns rows
// [blk*64 + w*16, +16), loops all 8 agents, register accumulator, plain stores.
// Stage cover: L3(a+1) issued at loop-end (covered by next phase 1); L1(a+1) issued
// before phase 3 (covered by phase 3); L2(a) published in two counted-vmcnt halves
// (tiles 0-3 compute covers tiles 4-7 latency). Tile-major gload assignment makes
// per-wave vmcnt counts exact (queue clean after B1's full drain).
__global__ void __launch_bounds__(256, 2)
qatten_main(const float* __restrict__ states,
            const float* __restrict__ b2g, const float* __restrict__ b3g,
            const float* __restrict__ ws2p, const float* __restrict__ bs2p,
            const float* __restrict__ wc2g, const float* __restrict__ bc2p,
            const unsigned short* __restrict__ wbuf,
            const float* __restrict__ b1e,
            float* __restrict__ out)
{
  __shared__ __align__(16) unsigned short bufMain[FB_L1*512];  // 44 KB (L1, then L2 in first 32KB)
  __shared__ __align__(16) unsigned short bufL3[FB_L3*512];    // 16 KB
  __shared__ __align__(16) unsigned short hlds[4 * 2048];      // 16 KB

  const int tid  = threadIdx.x;
  const int wave = tid >> 6;
  const int lane = tid & 63;
  const int lr   = lane & 15;
  const int lg   = lane >> 4;
  const int row0 = blockIdx.x * 64 + wave * 16;

  unsigned short* hp = hlds + wave * 2048;   // this wave's 4KB h region

  const float ws2  = ws2p[0];
  const float bs2v = bs2p[0];
  const float bc2v = bc2p[0];
  const float wc2a = wc2g[lr];
  const float wc2b = wc2g[16 + lr];

  const f32x4 zero4 = {0.f, 0.f, 0.f, 0.f};

  f32x4 out_acc[NJ3];
#pragma unroll
  for (int j = 0; j < NJ3; ++j) out_acc[j] = zero4;

  // ---- prologue: stage L1(0) + L3(0); prefetch agent-0 states & biases ----
  {
    const char* s0 = (const char*)wbuf;
    for (int t = wave; t < NJ1; t += 4)        // tile-major: wave w -> tiles w, w+4, w+8
#pragma unroll
      for (int c = 0; c < 4; ++c)
        gload_lds16(s0 + (t*4+c)*1024 + lane*16, (char*)bufMain + (t*4+c)*1024);
    const char* s3 = s0 + (size_t)(FB_L1+FB_L2)*1024;
    {
      int t = wave;                            // 4 tiles, wave w -> tile w
#pragma unroll
      for (int c = 0; c < 4; ++c)
        gload_lds16(s3 + (t*4+c)*1024 + lane*16, (char*)bufL3 + (t*4+c)*1024);
    }
  }

  f32x4 sreg[8];            // raw states for the NEXT agent (2 per kk)
  float b1n[NJ1], b2n[NJ2], b3n[NJ3];
  {
    const float* sb = states + (size_t)row0 * DDIM;     // agent 0
#pragma unroll
    for (int kk = 0; kk < 4; ++kk) {
      const float* p = sb + lr*DDIM + kk*32 + lg*8;
      sreg[kk*2]   = *(const f32x4*)p;
      sreg[kk*2+1] = *(const f32x4*)(p + 4);
    }
#pragma unroll
    for (int j = 0; j < NJ1; ++j) b1n[j] = b1e[j*16 + lr];
#pragma unroll
    for (int j = 0; j < NJ2; ++j) b2n[j] = b2g[j*16 + lr];
#pragma unroll
    for (int j = 0; j < NJ3; ++j) b3n[j] = b3g[j*16 + lr];
  }
  __syncthreads();                    // agent-0 L1+L3 published

  for (int a = 0; a < NAG; ++a) {
    // ---- consume prefetched biases ----
    float b1v[NJ1], b2v[NJ2], b3v[NJ3];
#pragma unroll
    for (int j = 0; j < NJ1; ++j) b1v[j] = b1n[j];
#pragma unroll
    for (int j = 0; j < NJ2; ++j) b2v[j] = b2n[j];
#pragma unroll
    for (int j = 0; j < NJ3; ++j) b3v[j] = b3n[j];

    // ---- convert prefetched states -> A1 fragments (pure VALU) ----
    bf16x8 afr[4];
#pragma unroll
    for (int kk = 0; kk < 4; ++kk) {
      f32x4 v0 = sreg[kk*2], v1 = sreg[kk*2+1];
      u32x4 w;
      w[0] = cvt_pk_bf16(v0[0], v0[1]);
      w[1] = cvt_pk_bf16(v0[2], v0[3]);
      w[2] = cvt_pk_bf16(v1[0], v1[1]);
      w[3] = cvt_pk_bf16(v1[2], v1[3]);
      afr[kk] = __builtin_bit_cast(bf16x8, w);
    }

    // ---- issue next agent's states loads (land under phase 1) ----
    if (a < NAG-1) {
      const float* sb = states + ((size_t)(a+1) * BATCH + row0) * DDIM;
#pragma unroll
      for (int kk = 0; kk < 4; ++kk) {
        const float* p = sb + lr*DDIM + kk*32 + lg*8;
        sreg[kk*2]   = *(const f32x4*)p;
        sreg[kk*2+1] = *(const f32x4*)(p + 4);
      }
    }

    // ---- phase 1: L1 (j=0..7) + gates (j=8..10) from bufMain, 2-deep pipelined ----
    f32x4 eacc[3];
    {
      bf16x8 pf[2][4];
#pragma unroll
      for (int kk = 0; kk < 4; ++kk)
        pf[0][kk] = *(const bf16x8*)&bufMain[kk*512 + lane*8];
#pragma unroll
      for (int j = 0; j < 11; ++j) {
        if (j < 10) {
#pragma unroll
          for (int kk = 0; kk < 4; ++kk)
            pf[(j+1)&1][kk] = *(const bf16x8*)&bufMain[((j+1)*4 + kk)*512 + lane*8];
        }
        f32x4 acc = zero4;
#pragma unroll
        for (int kk = 0; kk < 4; ++kk)
          acc = __builtin_amdgcn_mfma_f32_16x16x32_bf16(afr[kk], pf[j&1][kk], acc, 0, 0, 0);
        if (j < 8) {
#pragma unroll
          for (int r = 0; r < 4; ++r) {
            float hv = acc[r] + b1v[j];
            hv = hv > 0.f ? hv : 0.f;
            int row = lg*4 + r;
            int bo = row*256 + (((j*16 + lr)*2) ^ ((row & 7) << 4));   // XOR swizzle
            *(unsigned short*)((char*)hp + bo) = f2bf1(hv);
          }
        } else {
          eacc[j-8] = acc;
        }
      }
    }

    // ---- gate & constraint scalars ----
    float scl[4], crow[4];
#pragma unroll
    for (int r = 0; r < 4; ++r) {
      float c0 = eacc[0][r] + b1v[8];  c0 = c0 > 0.f ? c0 : 0.f;
      float c1 = eacc[1][r] + b1v[9];  c1 = c1 > 0.f ? c1 : 0.f;
      float cd = c0*wc2a + c1*wc2b;
      cd += __shfl_xor(cd, 1);
      cd += __shfl_xor(cd, 2);
      cd += __shfl_xor(cd, 4);
      cd += __shfl_xor(cd, 8);          // sum over 16 cols within lg-group
      crow[r] = cd + bc2v;
      float sp = eacc[2][r] + b1v[10];
      sp = __shfl(sp, lane & 48);       // broadcast col-160 (lr==0) value
      sp = sp > 0.f ? sp : 0.f;
      float s = ws2 * sp + bs2v;
      scl[r] = 1.f / (1.f + __expf(-s));
    }

    // ---- A2 fragments from own h region (own-wave DS in-order) ----
#pragma unroll
    for (int kk = 0; kk < 4; ++kk) {
      int row = lr;
      int bo = row*256 + ((kk*64 + lg*16) ^ ((row & 7) << 4));
      afr[kk] = *(const bf16x8*)((char*)hp + bo);
    }

    __syncthreads();   // B1: phase-1 reads of bufMain done; full vmcnt drain -> queue clean

    // ---- issue L2(a) -> bufMain (tile-major: wave w -> tiles w, w+4; 8 gloads/wave) ----
    {
      const char* s2 = (const char*)(wbuf + (size_t)a*WAGENT + FB_L1*512);
      for (int t = wave; t < NJ2; t += 4)
#pragma unroll
        for (int c = 0; c < 4; ++c)
          gload_lds16(s2 + (t*4+c)*1024 + lane*16, (char*)bufMain + (t*4+c)*1024);
    }

    // ---- publication half 1: tiles 0..3 (each wave's oldest 4 loads = its first tile) ----
    asm volatile("s_waitcnt vmcnt(4)" ::: "memory");
    __builtin_amdgcn_s_barrier();
    __builtin_amdgcn_sched_barrier(0);

    // ---- phase 2a: L2 j=0..3, 2-deep pipelined ----
    {
      bf16x8 pf[2][4];
#pragma unroll
      for (int kk = 0; kk < 4; ++kk)
        pf[0][kk] = *(const bf16x8*)&bufMain[kk*512 + lane*8];
#pragma unroll
      for (int j = 0; j < 4; ++j) {
        if (j < 3) {
#pragma unroll
          for (int kk = 0; kk < 4; ++kk)
            pf[(j+1)&1][kk] = *(const bf16x8*)&bufMain[((j+1)*4 + kk)*512 + lane*8];
        }
        f32x4 acc = zero4;
#pragma unroll
        for (int kk = 0; kk < 4; ++kk)
          acc = __builtin_amdgcn_mfma_f32_16x16x32_bf16(afr[kk], pf[j&1][kk], acc, 0, 0, 0);
#pragma unroll
        for (int r = 0; r < 4; ++r) {
          float hv = acc[r] + b2v[j];
          hv = hv > 0.f ? hv : 0.f;
          int row = lg*4 + r;
          int bo = row*256 + (((j*16 + lr)*2) ^ ((row & 7) << 4));
          *(unsigned short*)((char*)hp + bo) = f2bf1(hv);
        }
      }
    }

    // ---- publication half 2: tiles 4..7 ----
    asm volatile("s_waitcnt vmcnt(0)" ::: "memory");
    __builtin_amdgcn_s_barrier();
    __builtin_amdgcn_sched_barrier(0);

    // ---- phase 2b: L2 j=4..7 ----
    {
      bf16x8 pf[2][4];
#pragma unroll
      for (int kk = 0; kk < 4; ++kk)
        pf[0][kk] = *(const bf16x8*)&bufMain[(4*4 + kk)*512 + lane*8];
#pragma unroll
      for (int j = 4; j < 8; ++j) {
        if (j < 7) {
#pragma unroll
          for (int kk = 0; kk < 4; ++kk)
            pf[(j+1)&1][kk] = *(const bf16x8*)&bufMain[((j+1)*4 + kk)*512 + lane*8];
        }
        f32x4 acc = zero4;
#pragma unroll
        for (int kk = 0; kk < 4; ++kk)
          acc = __builtin_amdgcn_mfma_f32_16x16x32_bf16(afr[kk], pf[j&1][kk], acc, 0, 0, 0);
#pragma unroll
        for (int r = 0; r < 4; ++r) {
          float hv = acc[r] + b2v[j];
          hv = hv > 0.f ? hv : 0.f;
          int row = lg*4 + r;
          int bo = row*256 + (((j*16 + lr)*2) ^ ((row & 7) << 4));
          *(unsigned short*)((char*)hp + bo) = f2bf1(hv);
        }
      }
    }

    // ---- A3 fragments from h2 (own-wave DS in-order) ----
#pragma unroll
    for (int kk = 0; kk < 4; ++kk) {
      int row = lr;
      int bo = row*256 + ((kk*64 + lg*16) ^ ((row & 7) << 4));
      afr[kk] = *(const bf16x8*)((char*)hp + bo);
    }

    __syncthreads();   // B3: phase-2 reads of bufMain done

    // ---- issue L1(a+1) -> bufMain and biases(a+1) (covered by phase 3) ----
    if (a < NAG-1) {
      const char* sA = (const char*)(wbuf + (size_t)(a+1)*WAGENT);
      for (int t = wave; t < NJ1; t += 4)
#pragma unroll
        for (int c = 0; c < 4; ++c)
          gload_lds16(sA + (t*4+c)*1024 + lane*16, (char*)bufMain + (t*4+c)*1024);
#pragma unroll
      for (int j = 0; j < NJ1; ++j) b1n[j] = b1e[(a+1)*176 + j*16 + lr];
#pragma unroll
      for (int j = 0; j < NJ2; ++j) b2n[j] = b2g[(a+1)*HDIM + j*16 + lr];
#pragma unroll
      for (int j = 0; j < NJ3; ++j) b3n[j] = b3g[(a+1)*ADIM + j*16 + lr];
    }

    // ---- phase 3: L3 (j=0..3) from bufL3, 2-deep; gated accumulate ----
    {
      bf16x8 pf[2][4];
#pragma unroll
      for (int kk = 0; kk < 4; ++kk)
        pf[0][kk] = *(const bf16x8*)&bufL3[kk*512 + lane*8];
#pragma unroll
      for (int j = 0; j < NJ3; ++j) {
        if (j < NJ3-1) {
#pragma unroll
          for (int kk = 0; kk < 4; ++kk)
            pf[(j+1)&1][kk] = *(const bf16x8*)&bufL3[((j+1)*4 + kk)*512 + lane*8];
        }
        f32x4 acc = zero4;
#pragma unroll
        for (int kk = 0; kk < 4; ++kk)
          acc = __builtin_amdgcn_mfma_f32_16x16x32_bf16(afr[kk], pf[j&1][kk], acc, 0, 0, 0);
#pragma unroll
        for (int r = 0; r < 4; ++r)
          out_acc[j][r] += scl[r] * (acc[r] + b3v[j]) + crow[r];
      }
    }

    __syncthreads();   // B4: phase-3 reads of bufL3 done; drains L1(a+1) (phase-3-covered)

    // ---- issue L3(a+1) -> bufL3 (published at next B1, covered by next phase 1) ----
    if (a < NAG-1) {
      const char* s3 = (const char*)(wbuf + (size_t)(a+1)*WAGENT + (size_t)(FB_L1+FB_L2)*512);
      int t = wave;
#pragma unroll
      for (int c = 0; c < 4; ++c)
        gload_lds16(s3 + (t*4+c)*1024 + lane*16, (char*)bufL3 + (t*4+c)*1024);
    }
  }

  // ---- final store: out = mean over agents (deterministic, no atomics) ----
#pragma unroll
  for (int j = 0; j < NJ3; ++j)
#pragma unroll
    for (int r = 0; r < 4; ++r) {
      size_t row = (size_t)row0 + lg*4 + r;
      out[row*ADIM + j*16 + lr] = out_acc[j][r] * 0.125f;
    }
}

extern "C" void kernel_launch(void* const* d_in, const int* in_sizes, int n_in,
                              void* d_out, int out_size, void* d_ws, size_t ws_size,
                              hipStream_t stream)
{
  const float* states = (const float*)d_in[0];
  const float* W1  = (const float*)d_in[1];
  const float* b1  = (const float*)d_in[2];
  const float* W2  = (const float*)d_in[3];
  const float* b2  = (const float*)d_in[4];
  const float* W3  = (const float*)d_in[5];
  const float* b3  = (const float*)d_in[6];
  const float* Ws1 = (const float*)d_in[13];
  const float* bs1 = (const float*)d_in[14];
  const float* Ws2 = (const float*)d_in[15];
  const float* bs2 = (const float*)d_in[16];
  const float* Wc1 = (const float*)d_in[17];
  const float* bc1 = (const float*)d_in[18];
  const float* Wc2 = (const float*)d_in[19];
  const float* bc2 = (const float*)d_in[20];

  unsigned short* wbuf = (unsigned short*)d_ws;
  float* b1e = (float*)((char*)d_ws + (size_t)NAG * WAGENT * 2);

  dim3 pb(256), pg((NAG * WAGENT + 255) / 256);
  prep_weights<<<pg, pb, 0, stream>>>(W1, W2, W3, Wc1, Ws1, b1, bc1, bs1, wbuf, b1e);

  dim3 mb(256), mg(BATCH / 64);   // 512 blocks = 2 per CU, 4 waves each
  qatten_main<<<mg, mb, 0, stream>>>(states, b2, b3, Ws2, bs2, Wc2, bc2,
                                     wbuf, b1e, (float*)d_out);
}

// Round 14
// 62.030 us; speedup vs baseline: 1.0310x; 1.0310x over previous
//
#include <hip/hip_runtime.h>
#include <hip/hip_bf16.h>

#define NAG 8
#define BATCH 32768
#define DDIM 128
#define ADIM 64
#define HDIM 128

#define NJ1 11            // layer1 col tiles: 128 (W1) + 32 (Wc1) + 1 (Ws1) -> 176 cols
#define NJ2 8
#define NJ3 4
#define FB_L1 (NJ1*4)     // 44 frag blocks (44KB)
#define FB_L2 (NJ2*4)     // 32
#define FB_L3 (NJ3*4)     // 16
#define FB_TOT (FB_L1+FB_L2+FB_L3)  // 92
#define WAGENT (FB_TOT*512)         // 47104 ushort per agent (92KB)

typedef __attribute__((ext_vector_type(8))) short bf16x8;
typedef __attribute__((ext_vector_type(4))) float f32x4;
typedef __attribute__((ext_vector_type(4))) unsigned int u32x4;

static __device__ __forceinline__ unsigned short f2bf(float f) {
  unsigned int u = __builtin_bit_cast(unsigned int, f);
  u += 0x7fffu + ((u >> 16) & 1u);          // RNE (inputs are finite)
  return (unsigned short)(u >> 16);
}

static __device__ __forceinline__ unsigned int cvt_pk_bf16(float a, float b) {
  unsigned int r;
  asm("v_cvt_pk_bf16_f32 %0, %1, %2" : "=v"(r) : "v"(a), "v"(b));
  return r;
}

// single-value f32->bf16 via one cvt_pk op (RNE), low 16 bits valid
static __device__ __forceinline__ unsigned short f2bf1(float f) {
  unsigned int r;
  asm("v_cvt_pk_bf16_f32 %0, %1, %2" : "=v"(r) : "v"(f), "v"(f));
  return (unsigned short)r;
}

// async global->LDS, 16B per lane; LDS dest = uniform base + lane*16 (linear)
static __device__ __forceinline__ void gload_lds16(const void* g, void* l) {
  __builtin_amdgcn_global_load_lds(
      (const __attribute__((address_space(1))) unsigned int*)g,
      (__attribute__((address_space(3))) unsigned int*)l, 16, 0, 0);
}

// ---------------- prep: f32 weights -> bf16 B-fragment-linear layout (proven) ----------------
// frag block fb=(j,kk): 512 bf16; element l*8+t = W[k = kk*32 + (l>>4)*8 + t][col = j*16 + (l&15)]
__global__ void __launch_bounds__(256)
prep_weights(const float* __restrict__ W1, const float* __restrict__ W2,
             const float* __restrict__ W3, const float* __restrict__ Wc1,
             const float* __restrict__ Ws1, const float* __restrict__ b1,
             const float* __restrict__ bc1, const float* __restrict__ bs1,
             unsigned short* __restrict__ wbuf, float* __restrict__ b1e)
{
  int tid = blockIdx.x * 256 + threadIdx.x;
  if (tid < NAG * WAGENT) {
    int agent = tid / WAGENT;
    int rem   = tid % WAGENT;
    int fb = rem >> 9;
    int li = rem & 511;
    int l = li >> 3, t = li & 7;
    int lr = l & 15, lg = l >> 4;
    float v = 0.0f;
    if (fb < FB_L1) {
      int j = fb >> 2, kk = fb & 3;
      int col = j*16 + lr, k = kk*32 + lg*8 + t;
      if (col < 128)       v = W1[((size_t)agent*128 + k)*128 + col];
      else if (col < 160)  v = Wc1[k*32 + (col-128)];
      else if (col == 160) v = Ws1[k];
    } else if (fb < FB_L1 + FB_L2) {
      int f = fb - FB_L1;
      int j = f >> 2, kk = f & 3;
      int col = j*16 + lr, k = kk*32 + lg*8 + t;
      v = W2[((size_t)agent*128 + k)*128 + col];
    } else {
      int f = fb - FB_L1 - FB_L2;
      int j = f >> 2, kk = f & 3;
      int col = j*16 + lr, k = kk*32 + lg*8 + t;
      v = W3[((size_t)agent*128 + k)*64 + col];
    }
    wbuf[tid] = f2bf(v);
  }
  if (tid < NAG * 176) {     // extended layer-1 bias: [b1 | bc1 | bs1 | 0]
    int agent = tid / 176, col = tid % 176;
    float v = 0.0f;
    if (col < 128)       v = b1[agent*128 + col];
    else if (col < 160)  v = bc1[col - 128];
    else if (col == 160) v = bs1[0];
    b1e[tid] = v;
  }
}

// ---------------- main: 2 blocks/CU, bufMain(L1/L2) + bufL3 split, covered staging ----------
// 512 blocks x 256 threads (4 waves), 2 blocks/CU (LDS 76KB). Wave w owns rows
// [blk*64 + w*16, +16), loops all 8 agents, register accumulator, plain stores.
// 4 barriers/agent (same as R12). Coverage: L1(a+1) staged under phase 3;
// L3(a+1) staged under next phase 1; only L2(a)'s 32KB drain at B2 is uncovered
// (sibling block on the CU covers it). No sched_barrier pins, no counted vmcnt.
__global__ void __launch_bounds__(256, 2)
qatten_main(const float* __restrict__ states,
            const float* __restrict__ b2g, const float* __restrict__ b3g,
            const float* __restrict__ ws2p, const float* __restrict__ bs2p,
            const float* __restrict__ wc2g, const float* __restrict__ bc2p,
            const unsigned short* __restrict__ wbuf,
            const float* __restrict__ b1e,
            float* __restrict__ out)
{
  __shared__ __align__(16) unsigned short bufMain[FB_L1*512];  // 44 KB (L1; L2 in first 32KB)
  __shared__ __align__(16) unsigned short bufL3[FB_L3*512];    // 16 KB
  __shared__ __align__(16) unsigned short hlds[4 * 2048];      // 16 KB

  const int tid  = threadIdx.x;
  const int wave = tid >> 6;
  const int lane = tid & 63;
  const int lr   = lane & 15;
  const int lg   = lane >> 4;
  const int row0 = blockIdx.x * 64 + wave * 16;

  unsigned short* hp = hlds + wave * 2048;   // this wave's 4KB h region

  const float ws2  = ws2p[0];
  const float bs2v = bs2p[0];
  const float bc2v = bc2p[0];
  const float wc2a = wc2g[lr];
  const float wc2b = wc2g[16 + lr];

  const f32x4 zero4 = {0.f, 0.f, 0.f, 0.f};

  f32x4 out_acc[NJ3];
#pragma unroll
  for (int j = 0; j < NJ3; ++j) out_acc[j] = zero4;

  // ---- prologue: stage L1(0) + L3(0); prefetch agent-0 states & biases ----
  {
    const char* s0 = (const char*)wbuf;
    for (int t = wave; t < NJ1; t += 4)        // tile-major: wave w -> tiles w, w+4, w+8
#pragma unroll
      for (int c = 0; c < 4; ++c)
        gload_lds16(s0 + (t*4+c)*1024 + lane*16, (char*)bufMain + (t*4+c)*1024);
    const char* s3 = s0 + (size_t)(FB_L1+FB_L2)*1024;
    {
      int t = wave;                            // 4 tiles, wave w -> tile w
#pragma unroll
      for (int c = 0; c < 4; ++c)
        gload_lds16(s3 + (t*4+c)*1024 + lane*16, (char*)bufL3 + (t*4+c)*1024);
    }
  }

  f32x4 sreg[8];            // raw states for the NEXT agent (2 per kk)
  float b1n[NJ1], b2n[NJ2], b3n[NJ3];
  {
    const float* sb = states + (size_t)row0 * DDIM;     // agent 0
#pragma unroll
    for (int kk = 0; kk < 4; ++kk) {
      const float* p = sb + lr*DDIM + kk*32 + lg*8;
      sreg[kk*2]   = *(const f32x4*)p;
      sreg[kk*2+1] = *(const f32x4*)(p + 4);
    }
#pragma unroll
    for (int j = 0; j < NJ1; ++j) b1n[j] = b1e[j*16 + lr];
#pragma unroll
    for (int j = 0; j < NJ2; ++j) b2n[j] = b2g[j*16 + lr];
#pragma unroll
    for (int j = 0; j < NJ3; ++j) b3n[j] = b3g[j*16 + lr];
  }
  __syncthreads();                    // agent-0 L1+L3 published

  for (int a = 0; a < NAG; ++a) {
    // ---- consume prefetched biases ----
    float b1v[NJ1], b2v[NJ2], b3v[NJ3];
#pragma unroll
    for (int j = 0; j < NJ1; ++j) b1v[j] = b1n[j];
#pragma unroll
    for (int j = 0; j < NJ2; ++j) b2v[j] = b2n[j];
#pragma unroll
    for (int j = 0; j < NJ3; ++j) b3v[j] = b3n[j];

    // ---- convert prefetched states -> A1 fragments (pure VALU) ----
    bf16x8 afr[4];
#pragma unroll
    for (int kk = 0; kk < 4; ++kk) {
      f32x4 v0 = sreg[kk*2], v1 = sreg[kk*2+1];
      u32x4 w;
      w[0] = cvt_pk_bf16(v0[0], v0[1]);
      w[1] = cvt_pk_bf16(v0[2], v0[3]);
      w[2] = cvt_pk_bf16(v1[0], v1[1]);
      w[3] = cvt_pk_bf16(v1[2], v1[3]);
      afr[kk] = __builtin_bit_cast(bf16x8, w);
    }

    // ---- issue next agent's states loads (land under phase 1) ----
    if (a < NAG-1) {
      const float* sb = states + ((size_t)(a+1) * BATCH + row0) * DDIM;
#pragma unroll
      for (int kk = 0; kk < 4; ++kk) {
        const float* p = sb + lr*DDIM + kk*32 + lg*8;
        sreg[kk*2]   = *(const f32x4*)p;
        sreg[kk*2+1] = *(const f32x4*)(p + 4);
      }
    }

    // ---- phase 1: L1 (j=0..7) + gates (j=8..10) from bufMain, 3-deep pipelined ----
    f32x4 eacc[3];
    {
      bf16x8 pf[3][4];
#pragma unroll
      for (int kk = 0; kk < 4; ++kk) {
        pf[0][kk] = *(const bf16x8*)&bufMain[(0*4 + kk)*512 + lane*8];
        pf[1][kk] = *(const bf16x8*)&bufMain[(1*4 + kk)*512 + lane*8];
      }
#pragma unroll
      for (int j = 0; j < 11; ++j) {
        if (j + 2 <= 10) {
#pragma unroll
          for (int kk = 0; kk < 4; ++kk)
            pf[(j+2)%3][kk] = *(const bf16x8*)&bufMain[((j+2)*4 + kk)*512 + lane*8];
        }
        f32x4 acc = zero4;
#pragma unroll
        for (int kk = 0; kk < 4; ++kk)
          acc = __builtin_amdgcn_mfma_f32_16x16x32_bf16(afr[kk], pf[j%3][kk], acc, 0, 0, 0);
        if (j < 8) {
#pragma unroll
          for (int r = 0; r < 4; ++r) {
            float hv = acc[r] + b1v[j];
            hv = hv > 0.f ? hv : 0.f;
            int row = lg*4 + r;
            int bo = row*256 + (((j*16 + lr)*2) ^ ((row & 7) << 4));   // XOR swizzle
            *(unsigned short*)((char*)hp + bo) = f2bf1(hv);
          }
        } else {
          eacc[j-8] = acc;
        }
      }
    }

    // ---- gate & constraint scalars ----
    float scl[4], crow[4];
#pragma unroll
    for (int r = 0; r < 4; ++r) {
      float c0 = eacc[0][r] + b1v[8];  c0 = c0 > 0.f ? c0 : 0.f;
      float c1 = eacc[1][r] + b1v[9];  c1 = c1 > 0.f ? c1 : 0.f;
      float cd = c0*wc2a + c1*wc2b;
      cd += __shfl_xor(cd, 1);
      cd += __shfl_xor(cd, 2);
      cd += __shfl_xor(cd, 4);
      cd += __shfl_xor(cd, 8);          // sum over 16 cols within lg-group
      crow[r] = cd + bc2v;
      float sp = eacc[2][r] + b1v[10];
      sp = __shfl(sp, lane & 48);       // broadcast col-160 (lr==0) value
      sp = sp > 0.f ? sp : 0.f;
      float s = ws2 * sp + bs2v;
      scl[r] = 1.f / (1.f + __expf(-s));
    }

    // ---- A2 fragments from own h region (own-wave DS in-order) ----
#pragma unroll
    for (int kk = 0; kk < 4; ++kk) {
      int row = lr;
      int bo = row*256 + ((kk*64 + lg*16) ^ ((row & 7) << 4));
      afr[kk] = *(const bf16x8*)((char*)hp + bo);
    }

    __syncthreads();   // B1: phase-1 reads of bufMain done; drains L3(a) stage (phase-1-covered)

    // ---- issue L2(a) -> bufMain (only uncovered drain; sibling block covers) ----
    {
      const char* s2 = (const char*)(wbuf + (size_t)a*WAGENT + FB_L1*512);
      for (int t = wave; t < NJ2; t += 4)
#pragma unroll
        for (int c = 0; c < 4; ++c)
          gload_lds16(s2 + (t*4+c)*1024 + lane*16, (char*)bufMain + (t*4+c)*1024);
    }

    __syncthreads();   // B2: publishes L2(a)

    // ---- phase 2: L2 (j=0..7) from bufMain, 3-deep pipelined ----
    {
      bf16x8 pf[3][4];
#pragma unroll
      for (int kk = 0; kk < 4; ++kk) {
        pf[0][kk] = *(const bf16x8*)&bufMain[(0*4 + kk)*512 + lane*8];
        pf[1][kk] = *(const bf16x8*)&bufMain[(1*4 + kk)*512 + lane*8];
      }
#pragma unroll
      for (int j = 0; j < 8; ++j) {
        if (j + 2 <= 7) {
#pragma unroll
          for (int kk = 0; kk < 4; ++kk)
            pf[(j+2)%3][kk] = *(const bf16x8*)&bufMain[((j+2)*4 + kk)*512 + lane*8];
        }
        f32x4 acc = zero4;
#pragma unroll
        for (int kk = 0; kk < 4; ++kk)
          acc = __builtin_amdgcn_mfma_f32_16x16x32_bf16(afr[kk], pf[j%3][kk], acc, 0, 0, 0);
#pragma unroll
        for (int r = 0; r < 4; ++r) {
          float hv = acc[r] + b2v[j];
          hv = hv > 0.f ? hv : 0.f;
          int row = lg*4 + r;
          int bo = row*256 + (((j*16 + lr)*2) ^ ((row & 7) << 4));
          *(unsigned short*)((char*)hp + bo) = f2bf1(hv);   // overwrite h1 (A2 in regs)
        }
      }
    }

    // ---- A3 fragments from h2 (own-wave DS in-order) ----
#pragma unroll
    for (int kk = 0; kk < 4; ++kk) {
      int row = lr;
      int bo = row*256 + ((kk*64 + lg*16) ^ ((row & 7) << 4));
      afr[kk] = *(const bf16x8*)((char*)hp + bo);
    }

    __syncthreads();   // B3: phase-2 reads of bufMain done

    // ---- issue L1(a+1) -> bufMain and biases(a+1) (covered by phase 3) ----
    if (a < NAG-1) {
      const char* sA = (const char*)(wbuf + (size_t)(a+1)*WAGENT);
      for (int t = wave; t < NJ1; t += 4)
#pragma unroll
        for (int c = 0; c < 4; ++c)
          gload_lds16(sA + (t*4+c)*1024 + lane*16, (char*)bufMain + (t*4+c)*1024);
#pragma unroll
      for (int j = 0; j < NJ1; ++j) b1n[j] = b1e[(a+1)*176 + j*16 + lr];
#pragma unroll
      for (int j = 0; j < NJ2; ++j) b2n[j] = b2g[(a+1)*HDIM + j*16 + lr];
#pragma unroll
      for (int j = 0; j < NJ3; ++j) b3n[j] = b3g[(a+1)*ADIM + j*16 + lr];
    }

    // ---- phase 3: L3 (j=0..3) from bufL3, 2-deep; gated accumulate ----
    {
      bf16x8 pf[2][4];
#pragma unroll
      for (int kk = 0; kk < 4; ++kk)
        pf[0][kk] = *(const bf16x8*)&bufL3[kk*512 + lane*8];
#pragma unroll
      for (int j = 0; j < NJ3; ++j) {
        if (j < NJ3-1) {
#pragma unroll
          for (int kk = 0; kk < 4; ++kk)
            pf[(j+1)&1][kk] = *(const bf16x8*)&bufL3[((j+1)*4 + kk)*512 + lane*8];
        }
        f32x4 acc = zero4;
#pragma unroll
        for (int kk = 0; kk < 4; ++kk)
          acc = __builtin_amdgcn_mfma_f32_16x16x32_bf16(afr[kk], pf[j&1][kk], acc, 0, 0, 0);
#pragma unroll
        for (int r = 0; r < 4; ++r)
          out_acc[j][r] += scl[r] * (acc[r] + b3v[j]) + crow[r];
      }
    }

    __syncthreads();   // B4: phase-3 reads of bufL3 done; drains L1(a+1) (phase-3-covered)

    // ---- issue L3(a+1) -> bufL3 (covered by next phase 1, published at next B1) ----
    if (a < NAG-1) {
      const char* s3 = (const char*)(wbuf + (size_t)(a+1)*WAGENT + (size_t)(FB_L1+FB_L2)*512);
      int t = wave;
#pragma unroll
      for (int c = 0; c < 4; ++c)
        gload_lds16(s3 + (t*4+c)*1024 + lane*16, (char*)bufL3 + (t*4+c)*1024);
    }
  }

  // ---- final store: out = mean over agents (deterministic, no atomics) ----
#pragma unroll
  for (int j = 0; j < NJ3; ++j)
#pragma unroll
    for (int r = 0; r < 4; ++r) {
      size_t row = (size_t)row0 + lg*4 + r;
      out[row*ADIM + j*16 + lr] = out_acc[j][r] * 0.125f;
    }
}

extern "C" void kernel_launch(void* const* d_in, const int* in_sizes, int n_in,
                              void* d_out, int out_size, void* d_ws, size_t ws_size,
                              hipStream_t stream)
{
  const float* states = (const float*)d_in[0];
  const float* W1  = (const float*)d_in[1];
  const float* b1  = (const float*)d_in[2];
  const float* W2  = (const float*)d_in[3];
  const float* b2  = (const float*)d_in[4];
  const float* W3  = (const float*)d_in[5];
  const float* b3  = (const float*)d_in[6];
  const float* Ws1 = (const float*)d_in[13];
  const float* bs1 = (const float*)d_in[14];
  const float* Ws2 = (const float*)d_in[15];
  const float* bs2 = (const float*)d_in[16];
  const float* Wc1 = (const float*)d_in[17];
  const float* bc1 = (const float*)d_in[18];
  const float* Wc2 = (const float*)d_in[19];
  const float* bc2 = (const float*)d_in[20];

  unsigned short* wbuf = (unsigned short*)d_ws;
  float* b1e = (float*)((char*)d_ws + (size_t)NAG * WAGENT * 2);

  dim3 pb(256), pg((NAG * WAGENT + 255) / 256);
  prep_weights<<<pg, pb, 0, stream>>>(W1, W2, W3, Wc1, Ws1, b1, bc1, bs1, wbuf, b1e);

  dim3 mb(256), mg(BATCH / 64);   // 512 blocks = 2 per CU, 4 waves each
  qatten_main<<<mg, mb, 0, stream>>>(states, b2, b3, Ws2, bs2, Wc2, bc2,
                                     wbuf, b1e, (float*)d_out);
}